// Round 1
// baseline (2990.279 us; speedup 1.0000x reference)
//
#include <hip/hip_runtime.h>
#include <math.h>

// Problem constants
constexpr int TVL = 7500;   // T*V = 300*25
constexpr int CIN = 256;
constexpr int CO  = 256;
constexpr int KO  = 768;    // K * C_OUT
constexpr int KK3 = 2304;   // C_OUT * TK
#define BNEPS 1e-5f

// ---------------------------------------------------------------------------
// Kernel 1: 1x1 conv as GEMM. out1[ng][o][col] = sum_c W[o][c]*x[n][c][col] + b[o]
// A = conv_w [768 x 256] row-major, B = x[n] [256 x 7500], C = out1 [768 x 7500]
// 64x64 tile, BK=16, 256 threads, 4x4 microtile.
// ---------------------------------------------------------------------------
__global__ __launch_bounds__(256) void k1_conv1x1(
    const float* __restrict__ x, const float* __restrict__ W,
    const float* __restrict__ bias, float* __restrict__ out1, int n0)
{
    __shared__ __align__(16) float As[16][68];  // [k][row], pad 68 to break conflicts
    __shared__ __align__(16) float Bs[16][64];  // [k][col]

    const int tid = threadIdx.x;
    const int ng  = blockIdx.z;
    const float* xn   = x    + (size_t)(n0 + ng) * ((size_t)CIN * TVL);
    float*       outn = out1 + (size_t)ng * ((size_t)KO * TVL);
    const int rowBase = blockIdx.y * 64;
    const int colBase = blockIdx.x * 64;
    const bool full   = (colBase + 64 <= TVL);

    const int ar = tid >> 2, ak = (tid & 3) << 2;   // A staging: row, k-offset
    const int brow = tid >> 4, bcol = (tid & 15) << 2; // B staging
    const int ty = tid >> 4, tx = tid & 15;

    float acc[4][4];
    #pragma unroll
    for (int i = 0; i < 4; ++i)
        #pragma unroll
        for (int j = 0; j < 4; ++j) acc[i][j] = 0.f;

    for (int kk = 0; kk < CIN; kk += 16) {
        const float4 a4 = *(const float4*)(W + (size_t)(rowBase + ar) * CIN + kk + ak);
        As[ak + 0][ar] = a4.x; As[ak + 1][ar] = a4.y;
        As[ak + 2][ar] = a4.z; As[ak + 3][ar] = a4.w;

        const float* bp = xn + (size_t)(kk + brow) * TVL + colBase + bcol;
        float4 b4;
        if (full) {
            b4 = *(const float4*)bp;
        } else {
            const int col = colBase + bcol;
            b4.x = (col + 0 < TVL) ? bp[0] : 0.f;
            b4.y = (col + 1 < TVL) ? bp[1] : 0.f;
            b4.z = (col + 2 < TVL) ? bp[2] : 0.f;
            b4.w = (col + 3 < TVL) ? bp[3] : 0.f;
        }
        *(float4*)&Bs[brow][bcol] = b4;
        __syncthreads();

        #pragma unroll
        for (int p = 0; p < 16; ++p) {
            const float4 av = *(const float4*)&As[p][ty << 2];
            const float4 bv = *(const float4*)&Bs[p][tx << 2];
            acc[0][0] += av.x*bv.x; acc[0][1] += av.x*bv.y; acc[0][2] += av.x*bv.z; acc[0][3] += av.x*bv.w;
            acc[1][0] += av.y*bv.x; acc[1][1] += av.y*bv.y; acc[1][2] += av.y*bv.z; acc[1][3] += av.y*bv.w;
            acc[2][0] += av.z*bv.x; acc[2][1] += av.z*bv.y; acc[2][2] += av.z*bv.z; acc[2][3] += av.z*bv.w;
            acc[3][0] += av.w*bv.x; acc[3][1] += av.w*bv.y; acc[3][2] += av.w*bv.z; acc[3][3] += av.w*bv.w;
        }
        __syncthreads();
    }

    #pragma unroll
    for (int i = 0; i < 4; ++i) {
        const int row = rowBase + (ty << 2) + i;
        const float bv = bias[row];
        const int col = colBase + (tx << 2);
        float* dst = outn + (size_t)row * TVL + col;
        if (full) {
            float4 o;
            o.x = acc[i][0] + bv; o.y = acc[i][1] + bv;
            o.z = acc[i][2] + bv; o.w = acc[i][3] + bv;
            *(float4*)dst = o;
        } else {
            #pragma unroll
            for (int j = 0; j < 4; ++j)
                if (col + j < TVL) dst[j] = acc[i][j] + bv;
        }
    }
}

// ---------------------------------------------------------------------------
// Kernel 2: spatial graph contraction + BN1 + ReLU.
// h[ng][c][t][w] = relu(bn1( sum_{k,v} out1[ng][k*256+c][t][v] * (A*M)[k][v][w] ))
// One thread handles one (ng,c) and two consecutive t's (amortizes A*M LDS reads).
// ---------------------------------------------------------------------------
__global__ __launch_bounds__(256) void k2_sgc(
    const float* __restrict__ out1, const float* __restrict__ A,
    const float* __restrict__ Mm, const float* __restrict__ g1,
    const float* __restrict__ b1, const float* __restrict__ m1,
    const float* __restrict__ v1, float* __restrict__ h)
{
    __shared__ __align__(16) float AMs[3 * 25 * 28]; // row stride 28 -> 16B-aligned rows
    const int tid = threadIdx.x;
    for (int i = tid; i < 1875; i += 256)
        AMs[(i / 25) * 28 + (i % 25)] = A[i] * Mm[i];
    __syncthreads();

    const int r  = blockIdx.x * 256 + tid;
    const int t2 = r % 150;
    const int rc = r / 150;
    const int c  = rc & 255;
    const int ng = rc >> 8;
    const int t  = t2 * 2;

    const float* base = out1 + ((size_t)ng * KO + c) * TVL + t * 25;
    float o0[25], o1[25];
    #pragma unroll
    for (int w = 0; w < 25; ++w) { o0[w] = 0.f; o1[w] = 0.f; }

    for (int k = 0; k < 3; ++k) {
        const float* yp = base + (size_t)k * CO * TVL;
        float y0[25], y1[25];
        #pragma unroll
        for (int v = 0; v < 25; ++v) { y0[v] = yp[v]; y1[v] = yp[25 + v]; }
        const float* amk = &AMs[k * 25 * 28];
        for (int v = 0; v < 25; ++v) {
            const float* am = amk + v * 28;
            const float ya = y0[v], yb = y1[v];
            #pragma unroll
            for (int w = 0; w < 25; ++w) {
                const float a = am[w];
                o0[w] += ya * a;
                o1[w] += yb * a;
            }
        }
    }

    const float sc = g1[c] / sqrtf(v1[c] + BNEPS);
    const float bi = b1[c] - m1[c] * sc;
    float* hp = h + ((size_t)ng * CO + c) * TVL + t * 25;
    #pragma unroll
    for (int w = 0; w < 25; ++w) {
        const float va = o0[w] * sc + bi;
        const float vb = o1[w] * sc + bi;
        hp[w]      = va > 0.f ? va : 0.f;
        hp[25 + w] = vb > 0.f ? vb : 0.f;
    }
}

// ---------------------------------------------------------------------------
// Kernel 3: temporal conv (9 taps, pad 4) + BN2 + ReLU + residual, as implicit GEMM.
// A = tconv_w [256 x 2304] row-major (k = c*9+dt contiguous).
// B[k][col] = h[ng][c][col + (dt-4)*25] masked to [0,7500)  (exact im2col identity).
// out[n][o][col] = relu(bn2(acc + tb[o])) + x[n][o][col]
// ---------------------------------------------------------------------------
__global__ __launch_bounds__(256) void k3_tconv(
    const float* __restrict__ h, const float* __restrict__ W3,
    const float* __restrict__ tb, const float* __restrict__ g2,
    const float* __restrict__ b2, const float* __restrict__ m2,
    const float* __restrict__ v2, const float* __restrict__ x,
    float* __restrict__ out, int n0)
{
    __shared__ __align__(16) float As[16][68];
    __shared__ __align__(16) float Bs[16][64];

    const int tid = threadIdx.x;
    const int ng  = blockIdx.z;
    const float* hn = h + (size_t)ng * ((size_t)CO * TVL);
    const int rowBase = blockIdx.y * 64;
    const int colBase = blockIdx.x * 64;
    const bool full   = (colBase + 64 <= TVL);

    const int ar = tid >> 2, ak = (tid & 3) << 2;
    const int brow = tid >> 4, bcol = (tid & 15) << 2;
    const int ty = tid >> 4, tx = tid & 15;

    float acc[4][4];
    #pragma unroll
    for (int i = 0; i < 4; ++i)
        #pragma unroll
        for (int j = 0; j < 4; ++j) acc[i][j] = 0.f;

    for (int kk = 0; kk < KK3; kk += 16) {
        const float4 a4 = *(const float4*)(W3 + (size_t)(rowBase + ar) * KK3 + kk + ak);
        As[ak + 0][ar] = a4.x; As[ak + 1][ar] = a4.y;
        As[ak + 2][ar] = a4.z; As[ak + 3][ar] = a4.w;

        const int k  = kk + brow;
        const int c  = k / 9;
        const int dt = k - c * 9;
        const int shift = (dt - 4) * 25;
        const float* hc = hn + (size_t)c * TVL;
        const int col = colBase + bcol;
        float bvals[4];
        #pragma unroll
        for (int j = 0; j < 4; ++j) {
            const int cj  = col + j;
            const int off = cj + shift;
            bvals[j] = (cj < TVL && off >= 0 && off < TVL) ? hc[off] : 0.f;
        }
        float4 b4; b4.x = bvals[0]; b4.y = bvals[1]; b4.z = bvals[2]; b4.w = bvals[3];
        *(float4*)&Bs[brow][bcol] = b4;
        __syncthreads();

        #pragma unroll
        for (int p = 0; p < 16; ++p) {
            const float4 av = *(const float4*)&As[p][ty << 2];
            const float4 bv = *(const float4*)&Bs[p][tx << 2];
            acc[0][0] += av.x*bv.x; acc[0][1] += av.x*bv.y; acc[0][2] += av.x*bv.z; acc[0][3] += av.x*bv.w;
            acc[1][0] += av.y*bv.x; acc[1][1] += av.y*bv.y; acc[1][2] += av.y*bv.z; acc[1][3] += av.y*bv.w;
            acc[2][0] += av.z*bv.x; acc[2][1] += av.z*bv.y; acc[2][2] += av.z*bv.z; acc[2][3] += av.z*bv.w;
            acc[3][0] += av.w*bv.x; acc[3][1] += av.w*bv.y; acc[3][2] += av.w*bv.z; acc[3][3] += av.w*bv.w;
        }
        __syncthreads();
    }

    const float* xn = x   + (size_t)(n0 + ng) * ((size_t)CO * TVL);
    float*       on = out + (size_t)(n0 + ng) * ((size_t)CO * TVL);
    #pragma unroll
    for (int i = 0; i < 4; ++i) {
        const int row = rowBase + (ty << 2) + i;
        const float sc = g2[row] / sqrtf(v2[row] + BNEPS);
        const float bb = (tb[row] - m2[row]) * sc + b2[row];
        const int col = colBase + (tx << 2);
        const float* xp = xn + (size_t)row * TVL + col;
        float*       op = on + (size_t)row * TVL + col;
        if (full) {
            const float4 xv = *(const float4*)xp;
            float4 o;
            o.x = fmaxf(acc[i][0] * sc + bb, 0.f) + xv.x;
            o.y = fmaxf(acc[i][1] * sc + bb, 0.f) + xv.y;
            o.z = fmaxf(acc[i][2] * sc + bb, 0.f) + xv.z;
            o.w = fmaxf(acc[i][3] * sc + bb, 0.f) + xv.w;
            *(float4*)op = o;
        } else {
            #pragma unroll
            for (int j = 0; j < 4; ++j)
                if (col + j < TVL)
                    op[j] = fmaxf(acc[i][j] * sc + bb, 0.f) + xp[j];
        }
    }
}

// ---------------------------------------------------------------------------
extern "C" void kernel_launch(void* const* d_in, const int* in_sizes, int n_in,
                              void* d_out, int out_size, void* d_ws, size_t ws_size,
                              hipStream_t stream)
{
    const float* x  = (const float*)d_in[0];
    const float* A  = (const float*)d_in[1];
    // d_in[2] = att_A, unused by the reference path
    const float* Mm = (const float*)d_in[3];
    const float* cw = (const float*)d_in[4];
    const float* cb = (const float*)d_in[5];
    const float* g1 = (const float*)d_in[6];
    const float* b1 = (const float*)d_in[7];
    const float* m1 = (const float*)d_in[8];
    const float* v1 = (const float*)d_in[9];
    const float* tw = (const float*)d_in[10];
    const float* tb = (const float*)d_in[11];
    const float* g2 = (const float*)d_in[12];
    const float* b2 = (const float*)d_in[13];
    const float* m2 = (const float*)d_in[14];
    const float* v2 = (const float*)d_in[15];
    float* out = (float*)d_out;

    // Workspace per batch element: out1 (768*7500 f32) + h (256*7500 f32) = 30.72 MB.
    // Pick the largest group size g | 16 that fits ws_size (graceful under small ws).
    const size_t perN = ((size_t)KO + CO) * TVL * sizeof(float);
    int g = 16;
    while (g > 1 && (size_t)g * perN > ws_size) g >>= 1;

    float* out1 = (float*)d_ws;
    float* hbuf = out1 + (size_t)g * KO * TVL;

    for (int n0 = 0; n0 < 16; n0 += g) {
        dim3 gr1((TVL + 63) / 64, KO / 64, g);   // 118 x 12 x g
        hipLaunchKernelGGL(k1_conv1x1, gr1, dim3(256), 0, stream,
                           x, cw, cb, out1, n0);
        hipLaunchKernelGGL(k2_sgc, dim3(g * 150), dim3(256), 0, stream,
                           out1, A, Mm, g1, b1, m1, v1, hbuf);
        dim3 gr3((TVL + 63) / 64, CO / 64, g);   // 118 x 4 x g
        hipLaunchKernelGGL(k3_tconv, gr3, dim3(256), 0, stream,
                           hbuf, tw, tb, g2, b2, m2, v2, x, out, n0);
    }
}

// Round 2
// 1561.678 us; speedup vs baseline: 1.9148x; 1.9148x over previous
//
#include <hip/hip_runtime.h>
#include <math.h>

constexpr int TVL = 7500;   // T*V
constexpr int CIN = 256;
constexpr int CO  = 256;
constexpr int KO  = 768;    // K * C_OUT
constexpr int KK3 = 2304;   // C_OUT * TK (reordered k' = dt*256 + c)
#define BNEPS 1e-5f

typedef __attribute__((ext_vector_type(8))) short short8;   // 8 bf16 = 4 VGPRs
typedef __attribute__((ext_vector_type(4))) float f32x4;
typedef unsigned short ushortT;

// RNE float->bf16 (raw u16), and back
static __device__ __forceinline__ ushortT f2bf(float v) {
    unsigned x = __float_as_uint(v);
    unsigned r = (x + 0x7fffu + ((x >> 16) & 1u)) >> 16;
    return (ushortT)r;
}
static __device__ __forceinline__ float bf2f(ushortT u) {
    return __uint_as_float((unsigned)u << 16);
}

// ---------------------------------------------------------------------------
// Split weights: conv_w [768x256] -> hi/lo bf16, same layout.
// ---------------------------------------------------------------------------
__global__ void ksplit_w1(const float* __restrict__ w,
                          ushortT* __restrict__ dH, ushortT* __restrict__ dL)
{
    int i = blockIdx.x * 256 + threadIdx.x;
    if (i < KO * CIN) {
        float v = w[i];
        ushortT h = f2bf(v);
        dH[i] = h;
        dL[i] = f2bf(v - bf2f(h));
    }
}

// tconv_w [256][256][9] -> reordered [o][k'=dt*256+c] hi/lo bf16
__global__ void ksplit_w3(const float* __restrict__ w,
                          ushortT* __restrict__ dH, ushortT* __restrict__ dL)
{
    int i = blockIdx.x * 256 + threadIdx.x;
    if (i < CO * KK3) {
        int o = i / KK3, rem = i - o * KK3;
        int c = rem / 9, dt = rem - c * 9;
        float v = w[i];
        ushortT h = f2bf(v);
        int j = o * KK3 + dt * 256 + c;
        dH[j] = h;
        dL[j] = f2bf(v - bf2f(h));
    }
}

// ---------------------------------------------------------------------------
// Transpose+split: src [256][7500] f32 (per image z) -> dst [7500][256] bf16 hi/lo
// ---------------------------------------------------------------------------
__global__ __launch_bounds__(256) void ktrans_split(
    const float* __restrict__ src, ushortT* __restrict__ dH, ushortT* __restrict__ dL)
{
    __shared__ float tile[32][33];
    const int z = blockIdx.z;
    src += (size_t)z * CO * TVL;
    dH  += (size_t)z * TVL * 256;
    dL  += (size_t)z * TVL * 256;
    const int tx = threadIdx.x & 31, ty = threadIdx.x >> 5;
    const int wBase = blockIdx.x * 32, cBase = blockIdx.y * 32;
    #pragma unroll
    for (int i = 0; i < 4; ++i) {
        int r = ty + i * 8;
        int w = wBase + tx;
        tile[r][tx] = (w < TVL) ? src[(size_t)(cBase + r) * TVL + w] : 0.f;
    }
    __syncthreads();
    #pragma unroll
    for (int i = 0; i < 4; ++i) {
        int wr = ty + i * 8;
        int w = wBase + wr;
        if (w < TVL) {
            float v = tile[tx][wr];
            ushortT hi = f2bf(v);
            ushortT lo = f2bf(v - bf2f(hi));
            dH[(size_t)w * 256 + cBase + tx] = hi;
            dL[(size_t)w * 256 + cBase + tx] = lo;
        }
    }
}

// ---------------------------------------------------------------------------
// Kernel 1 (MFMA): out1[ng][o][col] = sum_c W[o][c]*x[ng][c][col] + b[o]
// A = W1 hi/lo [768x256]; B = xT hi/lo [col][c]; BM=BN=128, BK=32.
// ---------------------------------------------------------------------------
__global__ __launch_bounds__(256) void k1_mfma(
    const ushortT* __restrict__ Wh, const ushortT* __restrict__ Wl,
    const ushortT* __restrict__ Xh, const ushortT* __restrict__ Xl,
    const float* __restrict__ bias, float* __restrict__ out1)
{
    __shared__ short Ah[128][40], Al[128][40], Bh[128][40], Bl[128][40];
    const int tid = threadIdx.x;
    const int ng = blockIdx.z;
    const int rowBase = blockIdx.y * 128;
    const int colBase = blockIdx.x * 128;
    const ushortT* XhN = Xh + (size_t)ng * TVL * 256;
    const ushortT* XlN = Xl + (size_t)ng * TVL * 256;

    f32x4 acc[4][4];
    #pragma unroll
    for (int a = 0; a < 4; ++a)
        #pragma unroll
        for (int b = 0; b < 4; ++b) acc[a][b] = (f32x4){0.f, 0.f, 0.f, 0.f};

    const int sr = tid >> 2, sk = (tid & 3) << 3;
    const int wv = tid >> 6, lane = tid & 63;
    const int wy = wv >> 1, wx = wv & 1;
    const int q = lane >> 4, l15 = lane & 15;

    #pragma unroll 1
    for (int kk = 0; kk < CIN; kk += 32) {
        #pragma unroll
        for (int i = 0; i < 2; ++i) {
            int r = sr + i * 64;
            const size_t go = (size_t)(rowBase + r) * CIN + kk + sk;
            *(short8*)&Ah[r][sk] = *(const short8*)(Wh + go);
            *(short8*)&Al[r][sk] = *(const short8*)(Wl + go);
        }
        #pragma unroll
        for (int i = 0; i < 2; ++i) {
            int cidx = sr + i * 64;
            int bcol = colBase + cidx;
            short8 vh{}, vl{};
            if (bcol < TVL) {
                const size_t go = (size_t)bcol * 256 + kk + sk;
                vh = *(const short8*)(XhN + go);
                vl = *(const short8*)(XlN + go);
            }
            *(short8*)&Bh[cidx][sk] = vh;
            *(short8*)&Bl[cidx][sk] = vl;
        }
        __syncthreads();

        short8 ah[4], al[4], bh[4], bl[4];
        #pragma unroll
        for (int mi = 0; mi < 4; ++mi) {
            ah[mi] = *(const short8*)&Ah[wy * 64 + mi * 16 + l15][q * 8];
            al[mi] = *(const short8*)&Al[wy * 64 + mi * 16 + l15][q * 8];
        }
        #pragma unroll
        for (int ni = 0; ni < 4; ++ni) {
            bh[ni] = *(const short8*)&Bh[wx * 64 + ni * 16 + l15][q * 8];
            bl[ni] = *(const short8*)&Bl[wx * 64 + ni * 16 + l15][q * 8];
        }
        #pragma unroll
        for (int mi = 0; mi < 4; ++mi)
            #pragma unroll
            for (int ni = 0; ni < 4; ++ni) {
                acc[mi][ni] = __builtin_amdgcn_mfma_f32_16x16x32_bf16(ah[mi], bh[ni], acc[mi][ni], 0, 0, 0);
                acc[mi][ni] = __builtin_amdgcn_mfma_f32_16x16x32_bf16(ah[mi], bl[ni], acc[mi][ni], 0, 0, 0);
                acc[mi][ni] = __builtin_amdgcn_mfma_f32_16x16x32_bf16(al[mi], bh[ni], acc[mi][ni], 0, 0, 0);
            }
        __syncthreads();
    }

    float* out1n = out1 + (size_t)ng * KO * TVL;
    #pragma unroll
    for (int mi = 0; mi < 4; ++mi)
        #pragma unroll
        for (int rr = 0; rr < 4; ++rr) {
            const int row = rowBase + wy * 64 + mi * 16 + q * 4 + rr;
            const float bv = bias[row];
            #pragma unroll
            for (int ni = 0; ni < 4; ++ni) {
                const int col = colBase + wx * 64 + ni * 16 + l15;
                if (col < TVL)
                    out1n[(size_t)row * TVL + col] = acc[mi][ni][rr] + bv;
            }
        }
}

// ---------------------------------------------------------------------------
// Kernel 2: spatial graph contraction + BN1 + ReLU (unchanged, fp32 VALU).
// ---------------------------------------------------------------------------
__global__ __launch_bounds__(256) void k2_sgc(
    const float* __restrict__ out1, const float* __restrict__ A,
    const float* __restrict__ Mm, const float* __restrict__ g1,
    const float* __restrict__ b1, const float* __restrict__ m1,
    const float* __restrict__ v1, float* __restrict__ h)
{
    __shared__ __align__(16) float AMs[3 * 25 * 28];
    const int tid = threadIdx.x;
    for (int i = tid; i < 1875; i += 256)
        AMs[(i / 25) * 28 + (i % 25)] = A[i] * Mm[i];
    __syncthreads();

    const int r  = blockIdx.x * 256 + tid;
    const int t2 = r % 150;
    const int rc = r / 150;
    const int c  = rc & 255;
    const int ng = rc >> 8;
    const int t  = t2 * 2;

    const float* base = out1 + ((size_t)ng * KO + c) * TVL + t * 25;
    float o0[25], o1[25];
    #pragma unroll
    for (int w = 0; w < 25; ++w) { o0[w] = 0.f; o1[w] = 0.f; }

    for (int k = 0; k < 3; ++k) {
        const float* yp = base + (size_t)k * CO * TVL;
        float y0[25], y1[25];
        #pragma unroll
        for (int v = 0; v < 25; ++v) { y0[v] = yp[v]; y1[v] = yp[25 + v]; }
        const float* amk = &AMs[k * 25 * 28];
        for (int v = 0; v < 25; ++v) {
            const float* am = amk + v * 28;
            const float ya = y0[v], yb = y1[v];
            #pragma unroll
            for (int w = 0; w < 25; ++w) {
                const float a = am[w];
                o0[w] += ya * a;
                o1[w] += yb * a;
            }
        }
    }

    const float sc = g1[c] / sqrtf(v1[c] + BNEPS);
    const float bi = b1[c] - m1[c] * sc;
    float* hp = h + ((size_t)ng * CO + c) * TVL + t * 25;
    #pragma unroll
    for (int w = 0; w < 25; ++w) {
        const float va = o0[w] * sc + bi;
        const float vb = o1[w] * sc + bi;
        hp[w]      = va > 0.f ? va : 0.f;
        hp[25 + w] = vb > 0.f ? vb : 0.f;
    }
}

// ---------------------------------------------------------------------------
// Kernel 3 (MFMA): temporal conv + BN2 + ReLU + residual.
// A = W3' hi/lo [256][k'=dt*256+c]; B[k'][col] = hT[col+shift(dt)][c] (masked).
// ---------------------------------------------------------------------------
__global__ __launch_bounds__(256) void k3_mfma(
    const ushortT* __restrict__ Wh, const ushortT* __restrict__ Wl,
    const ushortT* __restrict__ Hh, const ushortT* __restrict__ Hl,
    const float* __restrict__ tb, const float* __restrict__ g2,
    const float* __restrict__ b2, const float* __restrict__ m2,
    const float* __restrict__ v2, const float* __restrict__ x,
    float* __restrict__ out, int n0)
{
    __shared__ short Ah[128][40], Al[128][40], Bh[128][40], Bl[128][40];
    const int tid = threadIdx.x;
    const int ng = blockIdx.z;
    const int rowBase = blockIdx.y * 128;
    const int colBase = blockIdx.x * 128;
    const ushortT* HhN = Hh + (size_t)ng * TVL * 256;
    const ushortT* HlN = Hl + (size_t)ng * TVL * 256;

    f32x4 acc[4][4];
    #pragma unroll
    for (int a = 0; a < 4; ++a)
        #pragma unroll
        for (int b = 0; b < 4; ++b) acc[a][b] = (f32x4){0.f, 0.f, 0.f, 0.f};

    const int sr = tid >> 2, sk = (tid & 3) << 3;
    const int wv = tid >> 6, lane = tid & 63;
    const int wy = wv >> 1, wx = wv & 1;
    const int q = lane >> 4, l15 = lane & 15;

    #pragma unroll 1
    for (int kk = 0; kk < KK3; kk += 32) {
        const int dt = kk >> 8;             // 2304 = 9*256; constant within BK=32
        const int c0 = kk & 255;
        const int shift = dt * 25 - 100;    // (dt-4)*25 in flattened t*25+v space
        #pragma unroll
        for (int i = 0; i < 2; ++i) {
            int r = sr + i * 64;
            const size_t go = (size_t)(rowBase + r) * KK3 + kk + sk;
            *(short8*)&Ah[r][sk] = *(const short8*)(Wh + go);
            *(short8*)&Al[r][sk] = *(const short8*)(Wl + go);
        }
        #pragma unroll
        for (int i = 0; i < 2; ++i) {
            int cidx = sr + i * 64;
            int bcol = colBase + cidx;
            int gcol = bcol + shift;
            short8 vh{}, vl{};
            if (bcol < TVL && (unsigned)gcol < (unsigned)TVL) {
                const size_t go = (size_t)gcol * 256 + c0 + sk;
                vh = *(const short8*)(HhN + go);
                vl = *(const short8*)(HlN + go);
            }
            *(short8*)&Bh[cidx][sk] = vh;
            *(short8*)&Bl[cidx][sk] = vl;
        }
        __syncthreads();

        short8 ah[4], al[4], bh[4], bl[4];
        #pragma unroll
        for (int mi = 0; mi < 4; ++mi) {
            ah[mi] = *(const short8*)&Ah[wy * 64 + mi * 16 + l15][q * 8];
            al[mi] = *(const short8*)&Al[wy * 64 + mi * 16 + l15][q * 8];
        }
        #pragma unroll
        for (int ni = 0; ni < 4; ++ni) {
            bh[ni] = *(const short8*)&Bh[wx * 64 + ni * 16 + l15][q * 8];
            bl[ni] = *(const short8*)&Bl[wx * 64 + ni * 16 + l15][q * 8];
        }
        #pragma unroll
        for (int mi = 0; mi < 4; ++mi)
            #pragma unroll
            for (int ni = 0; ni < 4; ++ni) {
                acc[mi][ni] = __builtin_amdgcn_mfma_f32_16x16x32_bf16(ah[mi], bh[ni], acc[mi][ni], 0, 0, 0);
                acc[mi][ni] = __builtin_amdgcn_mfma_f32_16x16x32_bf16(ah[mi], bl[ni], acc[mi][ni], 0, 0, 0);
                acc[mi][ni] = __builtin_amdgcn_mfma_f32_16x16x32_bf16(al[mi], bh[ni], acc[mi][ni], 0, 0, 0);
            }
        __syncthreads();
    }

    const float* xn = x   + (size_t)(n0 + ng) * CO * TVL;
    float*       on = out + (size_t)(n0 + ng) * CO * TVL;
    #pragma unroll
    for (int mi = 0; mi < 4; ++mi)
        #pragma unroll
        for (int rr = 0; rr < 4; ++rr) {
            const int row = rowBase + wy * 64 + mi * 16 + q * 4 + rr;
            const float sc = g2[row] / sqrtf(v2[row] + BNEPS);
            const float bb = (tb[row] - m2[row]) * sc + b2[row];
            #pragma unroll
            for (int ni = 0; ni < 4; ++ni) {
                const int col = colBase + wx * 64 + ni * 16 + l15;
                if (col < TVL) {
                    const size_t o = (size_t)row * TVL + col;
                    on[o] = fmaxf(acc[mi][ni][rr] * sc + bb, 0.f) + xn[o];
                }
            }
        }
}

// ---------------------------------------------------------------------------
extern "C" void kernel_launch(void* const* d_in, const int* in_sizes, int n_in,
                              void* d_out, int out_size, void* d_ws, size_t ws_size,
                              hipStream_t stream)
{
    const float* x  = (const float*)d_in[0];
    const float* A  = (const float*)d_in[1];
    const float* Mm = (const float*)d_in[3];
    const float* cw = (const float*)d_in[4];
    const float* cb = (const float*)d_in[5];
    const float* g1 = (const float*)d_in[6];
    const float* b1 = (const float*)d_in[7];
    const float* m1 = (const float*)d_in[8];
    const float* v1 = (const float*)d_in[9];
    const float* tw = (const float*)d_in[10];
    const float* tb = (const float*)d_in[11];
    const float* g2 = (const float*)d_in[12];
    const float* b2 = (const float*)d_in[13];
    const float* m2 = (const float*)d_in[14];
    const float* v2 = (const float*)d_in[15];
    float* out = (float*)d_out;

    // Workspace layout: split weights first (fixed), then per-group buffers.
    ushortT* W1h = (ushortT*)d_ws;                 // 768*256
    ushortT* W1l = W1h + KO * CIN;
    ushortT* W3h = W1l + KO * CIN;                 // 256*2304
    ushortT* W3l = W3h + CO * KK3;
    char* dyn = (char*)(W3l + CO * KK3);
    const size_t fixed = (size_t)(dyn - (char*)d_ws);
    const size_t avail = ws_size > fixed ? ws_size - fixed : 0;
    // per-n: out1 f32 + h f32 + hT hi/lo bf16 + xT hi/lo bf16
    const size_t perN = (size_t)KO * TVL * 4 + (size_t)CO * TVL * 4
                      + 4 * (size_t)TVL * 256 * 2;
    int g = 16;
    while (g > 1 && (size_t)g * perN > avail) g >>= 1;

    float*   out1 = (float*)dyn;
    float*   hbuf = out1 + (size_t)g * KO * TVL;
    ushortT* Hh   = (ushortT*)(hbuf + (size_t)g * CO * TVL);
    ushortT* Hl   = Hh + (size_t)g * TVL * 256;
    ushortT* Xh   = Hl + (size_t)g * TVL * 256;
    ushortT* Xl   = Xh + (size_t)g * TVL * 256;

    hipLaunchKernelGGL(ksplit_w1, dim3((KO * CIN + 255) / 256), dim3(256), 0, stream, cw, W1h, W1l);
    hipLaunchKernelGGL(ksplit_w3, dim3((CO * KK3 + 255) / 256), dim3(256), 0, stream, tw, W3h, W3l);

    for (int n0 = 0; n0 < 16; n0 += g) {
        hipLaunchKernelGGL(ktrans_split, dim3(235, 8, g), dim3(256), 0, stream,
                           x + (size_t)n0 * CIN * TVL, Xh, Xl);
        hipLaunchKernelGGL(k1_mfma, dim3(59, 6, g), dim3(256), 0, stream,
                           W1h, W1l, Xh, Xl, cb, out1);
        hipLaunchKernelGGL(k2_sgc, dim3(g * 150), dim3(256), 0, stream,
                           out1, A, Mm, g1, b1, m1, v1, hbuf);
        hipLaunchKernelGGL(ktrans_split, dim3(235, 8, g), dim3(256), 0, stream,
                           hbuf, Hh, Hl);
        hipLaunchKernelGGL(k3_mfma, dim3(59, 2, g), dim3(256), 0, stream,
                           W3h, W3l, Hh, Hl, tb, g2, b2, m2, v2, x, out, n0);
    }
}